// Round 5
// baseline (452.299 us; speedup 1.0000x reference)
//
#include <hip/hip_runtime.h>
#include <hip/hip_bf16.h>
#include <stdint.h>

// CA model: B=8, H=256, W=256, C=16, HID=128, steps=2 (fixed by setup_inputs).
// Per step: y=[x,sobel1,sobel2] (48) -> h=relu(y@W0^T+b0) (128) -> dx=h@W1^T (16)
// -> x' = x + dx*mask (channels 3: only). MLP on bf16 MFMA (16x16x32),
// residual/update path in fp32. Mask: JAX threefry2x32 partitionable bits.
// Round 5: TW 64->32 (4096 blocks, 29.4KB LDS, 4 resident blocks/CU) for
// latency hiding; compute structure identical to round-4 passing kernel.

#define NB 8
#define NH 256
#define NW 256
#define NC 16
#define TH 4
#define TW 32

typedef __attribute__((ext_vector_type(8))) short short8;
typedef __attribute__((ext_vector_type(4))) float floatx4;
typedef __attribute__((ext_vector_type(2))) uint32_t uint32x2;

__host__ __device__ inline void tf2x32(uint32_t k0, uint32_t k1,
                                       uint32_t x0, uint32_t x1,
                                       uint32_t& o0, uint32_t& o1) {
  const uint32_t ks2 = k0 ^ k1 ^ 0x1BD11BDAu;
  x0 += k0; x1 += k1;
#define RL(v, d) (((v) << (d)) | ((v) >> (32 - (d))))
#define R4(a, b, c, d)                          \
  x0 += x1; x1 = RL(x1, a); x1 ^= x0;           \
  x0 += x1; x1 = RL(x1, b); x1 ^= x0;           \
  x0 += x1; x1 = RL(x1, c); x1 ^= x0;           \
  x0 += x1; x1 = RL(x1, d); x1 ^= x0;
  R4(13, 15, 26, 6);  x0 += k1;  x1 += ks2 + 1u;
  R4(17, 29, 16, 24); x0 += ks2; x1 += k0 + 2u;
  R4(13, 15, 26, 6);  x0 += k0;  x1 += k1 + 3u;
  R4(17, 29, 16, 24); x0 += k1;  x1 += ks2 + 4u;
  R4(13, 15, 26, 6);  x0 += ks2; x1 += k0 + 5u;
#undef R4
#undef RL
  o0 = x0; o1 = x1;
}

__device__ inline short bfr(float x) {
  __hip_bfloat16 h = __float2bfloat16(x);
  return *reinterpret_cast<short*>(&h);
}

__global__ __launch_bounds__(256, 4) void ca_step(
    const float* __restrict__ xin, float* __restrict__ xout,
    const float* __restrict__ W0, const float* __restrict__ b0,
    const float* __restrict__ W1, uint32_t fk0, uint32_t fk1) {
  // fp32 x tile + halo, 16B-chunk XOR-swizzled (bijective; same map at
  // stage and read)
  __shared__ float xs[6 * 34 * 16];
  __shared__ __align__(16) uint8_t ht[4][4096];   // per-wave H^T bounce (bf16)

  const int tid = threadIdx.x;
  const int bt = blockIdx.x;
  const int wt = bt & 7;
  const int htile = (bt >> 3) & 63;
  const int b = bt >> 9;
  const int h0 = htile * TH;
  const int w0 = wt * TW;

  const int lane = tid & 63;
  const int wv = tid >> 6;
  const int c15 = lane & 15;
  const int g = lane >> 4;

  auto xsaddr = [&](int row, int col, int chunk) -> floatx4* {
    const int off = (row * 34 + col) * 64 + ((chunk ^ ((col >> 1) & 3)) << 4);
    return reinterpret_cast<floatx4*>(reinterpret_cast<char*>(xs) + off);
  };

  // ---- prologue: weight fragments held in VGPRs for whole kernel ----
  // GEMM1': H^T = W0 . Y^T  (A-frag: lane holds A[row=c15][k=8g+j])
  short8 w0f[8][2];
  floatx4 bias4[8];
  short8 w1f[4];
#pragma unroll
  for (int n = 0; n < 8; ++n) {
    const int o = 16 * n + c15;
    const float* p = W0 + o * 48 + 8 * g;
    short8 f;
#pragma unroll
    for (int j = 0; j < 8; ++j) f[j] = bfr(p[j]);
    w0f[n][0] = f;
    short8 f1;
    if (g < 2) {
      const float* p1 = W0 + o * 48 + 32 + 8 * g;
#pragma unroll
      for (int j = 0; j < 8; ++j) f1[j] = bfr(p1[j]);
    } else {
#pragma unroll
      for (int j = 0; j < 8; ++j) f1[j] = 0;   // K-pad 48..63
    }
    w0f[n][1] = f1;
    bias4[n] = *reinterpret_cast<const floatx4*>(b0 + 16 * n + 4 * g);
  }
#pragma unroll
  for (int s = 0; s < 4; ++s) {   // GEMM2': A = W1 [16 ch x 128 o]
    const float* p = W1 + c15 * 128 + 32 * s + 8 * g;
    short8 f;
#pragma unroll
    for (int j = 0; j < 8; ++j) f[j] = bfr(p[j]);
    w1f[s] = f;
  }

  // per-lane sobel tap weights: groups 0/1 produce c2 (sobel2), 2/3 c1 (sobel1)
  float wts[8];
  {
    const float Ac[3] = {1.f, 2.f, 1.f};
    const float Bc[3] = {-1.f, 0.f, 1.f};
    int t = 0;
#pragma unroll
    for (int dh = -1; dh <= 1; ++dh)
#pragma unroll
      for (int dw = -1; dw <= 1; ++dw) {
        if (dh == 0 && dw == 0) continue;
        const float wA = Ac[dw + 1] * Bc[dh + 1] * 0.125f;  // c1
        const float wB = Ac[dh + 1] * Bc[dw + 1] * 0.125f;  // c2
        wts[t++] = (g < 2) ? wB : wA;
      }
  }

  // ---- stage x tile (fp32, zero-padded halo, swizzled) ----
  for (int f = tid; f < 6 * 34 * 4; f += 256) {
    const int row = f / 136;
    const int rem = f - row * 136;
    const int col = rem >> 2;
    const int q = rem & 3;
    const int gh = h0 - 1 + row;
    const int gw = w0 - 1 + col;
    floatx4 v = {0.f, 0.f, 0.f, 0.f};
    if ((unsigned)gh < (unsigned)NH && (unsigned)gw < (unsigned)NW)
      v = *reinterpret_cast<const floatx4*>(
          xin + (((size_t)b * NH + gh) * NW + gw) * NC + 4 * q);
    *xsaddr(row, col, q) = v;
  }

  // ---- fire mask: one threefry per cell, wave keeps ballot (bits 0..31) ----
  uint64_t mball;
  {
    const int cellg = (b * NH + h0 + wv) * NW + w0 + (lane & 31);
    uint32_t r0, r1;
    tf2x32(fk0, fk1, 0u, (uint32_t)cellg, r0, r1);
    const uint32_t bits = r0 ^ r1;
    const float u = __uint_as_float((bits >> 9) | 0x3F800000u) - 1.0f;
    mball = __ballot(u > 0.5f);
  }
  __syncthreads();

  const int cc = 2 * (g & 1);   // chunk pair base for this lane's 8 channels
  const int r = wv + 1;
  uint8_t* hbase = ht[wv];

#pragma unroll
  for (int mt = 0; mt < 2; ++mt) {
    const int col = 1 + 16 * mt + c15;

    // center x (identity part of y for groups 0/1)
    const floatx4 xc0 = *xsaddr(r, col, cc);
    const floatx4 xc1 = *xsaddr(r, col, cc + 1);

    // branchless 8-tap sobel over this lane's 8 channels
    float sob[8];
#pragma unroll
    for (int j = 0; j < 8; ++j) sob[j] = 0.f;
    int t = 0;
#pragma unroll
    for (int dh = -1; dh <= 1; ++dh)
#pragma unroll
      for (int dw = -1; dw <= 1; ++dw) {
        if (dh == 0 && dw == 0) continue;
        const floatx4 v0 = *xsaddr(r + dh, col + dw, cc);
        const floatx4 v1 = *xsaddr(r + dh, col + dw, cc + 1);
        const float w = wts[t++];
        sob[0] += w * v0.x; sob[1] += w * v0.y;
        sob[2] += w * v0.z; sob[3] += w * v0.w;
        sob[4] += w * v1.x; sob[5] += w * v1.y;
        sob[6] += w * v1.z; sob[7] += w * v1.w;
      }

    // Y^T B-fragments: a0 -> k 0..31 (x | c1), a1 -> k 32..63 (c2 | pad)
    const bool lo = (g < 2);
    const float xcv[8] = {xc0.x, xc0.y, xc0.z, xc0.w, xc1.x, xc1.y, xc1.z, xc1.w};
    short8 a0, a1;
#pragma unroll
    for (int j = 0; j < 8; ++j) {
      const short sb = bfr(sob[j]);
      a0[j] = lo ? bfr(xcv[j]) : sb;
      a1[j] = lo ? sb : (short)0;
    }

    // GEMM1': 16 MFMAs -> H^T tiles (row o, col cell)
    floatx4 acc[8];
#pragma unroll
    for (int n = 0; n < 8; ++n) acc[n] = bias4[n];
#pragma unroll
    for (int n = 0; n < 8; ++n)
      acc[n] = __builtin_amdgcn_mfma_f32_16x16x32_bf16(w0f[n][0], a0, acc[n], 0, 0, 0);
#pragma unroll
    for (int n = 0; n < 8; ++n)
      acc[n] = __builtin_amdgcn_mfma_f32_16x16x32_bf16(w0f[n][1], a1, acc[n], 0, 0, 0);

    // compiler barrier: prior-iteration ht reads may not sink below the
    // stores (uint32x2 stores vs short8 loads are TBAA-distinct)
    asm volatile("" ::: "memory");

    // relu -> bf16 -> per-wave LDS bounce (XOR swizzle vs 256B-stride conflicts)
#pragma unroll
    for (int n = 0; n < 8; ++n) {
      const float r0 = fmaxf(acc[n].x, 0.f), r1 = fmaxf(acc[n].y, 0.f);
      const float r2 = fmaxf(acc[n].z, 0.f), r3 = fmaxf(acc[n].w, 0.f);
      uint32x2 u;
      u.x = (uint32_t)(uint16_t)bfr(r0) | ((uint32_t)(uint16_t)bfr(r1) << 16);
      u.y = (uint32_t)(uint16_t)bfr(r2) | ((uint32_t)(uint16_t)bfr(r3) << 16);
      int byte = c15 * 256 + (16 * n + 4 * g) * 2;
      byte ^= (c15 & 7) << 4;
      *reinterpret_cast<uint32x2*>(hbase + byte) = u;
    }

    // GEMM2': dx^T = W1 . H   (B-frag = H^T[k=o][cell]), 4 MFMAs
    floatx4 acc2 = {0.f, 0.f, 0.f, 0.f};
#pragma unroll
    for (int s = 0; s < 4; ++s) {
      int byte = c15 * 256 + (32 * s + 8 * g) * 2;
      byte ^= (c15 & 7) << 4;
      const short8 b2 = *reinterpret_cast<short8*>(hbase + byte);
      acc2 = __builtin_amdgcn_mfma_f32_16x16x32_bf16(w1f[s], b2, acc2, 0, 0, 0);
    }

    // update: lane holds dx[ch=4g+reg][cell=c15]; fp32 residual path
    const floatx4 xv = *xsaddr(r, col, g);
    const float mk = (float)((mball >> (16 * mt + c15)) & 1ull);
    const float mk03 = (g == 0) ? 0.f : mk;   // channels 0..2 frozen
    floatx4 ov;
    ov.x = xv.x + acc2.x * mk03;
    ov.y = xv.y + acc2.y * mk03;
    ov.z = xv.z + acc2.z * mk03;
    ov.w = xv.w + acc2.w * mk;
    const size_t cellg = ((size_t)(b * NH + h0 + wv)) * NW + w0 + 16 * mt + c15;
    *reinterpret_cast<floatx4*>(xout + cellg * NC + 4 * g) = ov;
  }
}

extern "C" void kernel_launch(void* const* d_in, const int* in_sizes, int n_in,
                              void* d_out, int out_size, void* d_ws, size_t ws_size,
                              hipStream_t stream) {
  const float* x  = (const float*)d_in[0];
  const float* W0 = (const float*)d_in[1];
  const float* b0 = (const float*)d_in[2];
  const float* W1 = (const float*)d_in[3];
  float* tmp = (float*)d_ws;
  float* out = (float*)d_out;

  uint32_t fa0, fa1, fb0, fb1;
  tf2x32(0u, 42u, 0u, 0u, fa0, fa1);  // fold_in(key(42), 0)
  tf2x32(0u, 42u, 0u, 1u, fb0, fb1);  // fold_in(key(42), 1)

  dim3 grid(NB * (NH / TH) * (NW / TW)), block(256);
  ca_step<<<grid, block, 0, stream>>>(x, tmp, W0, b0, W1, fa0, fa1);
  ca_step<<<grid, block, 0, stream>>>(tmp, out, W0, b0, W1, fb0, fb1);
}

// Round 6
// 135.276 us; speedup vs baseline: 3.3435x; 3.3435x over previous
//
#include <hip/hip_runtime.h>
#include <hip/hip_bf16.h>
#include <stdint.h>

// CA model: B=8, H=256, W=256, C=16, HID=128, steps=2 (fixed by setup_inputs).
// Per step: y=[x,sobel1,sobel2] (48) -> h=relu(y@W0^T+b0) (128) -> dx=h@W1^T (16)
// -> x' = x + dx*mask (channels 3: only). MLP on bf16 MFMA (16x16x32),
// residual/update path in fp32. Mask: JAX threefry2x32 partitionable bits.
// Round 6: round-5 kernel with __launch_bounds__(256,2) — the (256,4) bound
// forced a 64-VGPR budget and spilled the resident weight fragments to
// scratch (FETCH 458MB/dispatch). TW=32 grid (4096 blocks) retained.

#define NB 8
#define NH 256
#define NW 256
#define NC 16
#define TH 4
#define TW 32

typedef __attribute__((ext_vector_type(8))) short short8;
typedef __attribute__((ext_vector_type(4))) float floatx4;
typedef __attribute__((ext_vector_type(2))) uint32_t uint32x2;

__host__ __device__ inline void tf2x32(uint32_t k0, uint32_t k1,
                                       uint32_t x0, uint32_t x1,
                                       uint32_t& o0, uint32_t& o1) {
  const uint32_t ks2 = k0 ^ k1 ^ 0x1BD11BDAu;
  x0 += k0; x1 += k1;
#define RL(v, d) (((v) << (d)) | ((v) >> (32 - (d))))
#define R4(a, b, c, d)                          \
  x0 += x1; x1 = RL(x1, a); x1 ^= x0;           \
  x0 += x1; x1 = RL(x1, b); x1 ^= x0;           \
  x0 += x1; x1 = RL(x1, c); x1 ^= x0;           \
  x0 += x1; x1 = RL(x1, d); x1 ^= x0;
  R4(13, 15, 26, 6);  x0 += k1;  x1 += ks2 + 1u;
  R4(17, 29, 16, 24); x0 += ks2; x1 += k0 + 2u;
  R4(13, 15, 26, 6);  x0 += k0;  x1 += k1 + 3u;
  R4(17, 29, 16, 24); x0 += k1;  x1 += ks2 + 4u;
  R4(13, 15, 26, 6);  x0 += ks2; x1 += k0 + 5u;
#undef R4
#undef RL
  o0 = x0; o1 = x1;
}

__device__ inline short bfr(float x) {
  __hip_bfloat16 h = __float2bfloat16(x);
  return *reinterpret_cast<short*>(&h);
}

__global__ __launch_bounds__(256, 2) void ca_step(
    const float* __restrict__ xin, float* __restrict__ xout,
    const float* __restrict__ W0, const float* __restrict__ b0,
    const float* __restrict__ W1, uint32_t fk0, uint32_t fk1) {
  // fp32 x tile + halo, 16B-chunk XOR-swizzled (bijective; same map at
  // stage and read)
  __shared__ float xs[6 * 34 * 16];
  __shared__ __align__(16) uint8_t ht[4][4096];   // per-wave H^T bounce (bf16)

  const int tid = threadIdx.x;
  const int bt = blockIdx.x;
  const int wt = bt & 7;
  const int htile = (bt >> 3) & 63;
  const int b = bt >> 9;
  const int h0 = htile * TH;
  const int w0 = wt * TW;

  const int lane = tid & 63;
  const int wv = tid >> 6;
  const int c15 = lane & 15;
  const int g = lane >> 4;

  auto xsaddr = [&](int row, int col, int chunk) -> floatx4* {
    const int off = (row * 34 + col) * 64 + ((chunk ^ ((col >> 1) & 3)) << 4);
    return reinterpret_cast<floatx4*>(reinterpret_cast<char*>(xs) + off);
  };

  // ---- prologue: weight fragments held in VGPRs for whole kernel ----
  // GEMM1': H^T = W0 . Y^T  (A-frag: lane holds A[row=c15][k=8g+j])
  short8 w0f[8][2];
  floatx4 bias4[8];
  short8 w1f[4];
#pragma unroll
  for (int n = 0; n < 8; ++n) {
    const int o = 16 * n + c15;
    const float* p = W0 + o * 48 + 8 * g;
    short8 f;
#pragma unroll
    for (int j = 0; j < 8; ++j) f[j] = bfr(p[j]);
    w0f[n][0] = f;
    short8 f1;
    if (g < 2) {
      const float* p1 = W0 + o * 48 + 32 + 8 * g;
#pragma unroll
      for (int j = 0; j < 8; ++j) f1[j] = bfr(p1[j]);
    } else {
#pragma unroll
      for (int j = 0; j < 8; ++j) f1[j] = 0;   // K-pad 48..63
    }
    w0f[n][1] = f1;
    bias4[n] = *reinterpret_cast<const floatx4*>(b0 + 16 * n + 4 * g);
  }
#pragma unroll
  for (int s = 0; s < 4; ++s) {   // GEMM2': A = W1 [16 ch x 128 o]
    const float* p = W1 + c15 * 128 + 32 * s + 8 * g;
    short8 f;
#pragma unroll
    for (int j = 0; j < 8; ++j) f[j] = bfr(p[j]);
    w1f[s] = f;
  }

  // per-lane sobel tap weights: groups 0/1 produce c2 (sobel2), 2/3 c1 (sobel1)
  float wts[8];
  {
    const float Ac[3] = {1.f, 2.f, 1.f};
    const float Bc[3] = {-1.f, 0.f, 1.f};
    int t = 0;
#pragma unroll
    for (int dh = -1; dh <= 1; ++dh)
#pragma unroll
      for (int dw = -1; dw <= 1; ++dw) {
        if (dh == 0 && dw == 0) continue;
        const float wA = Ac[dw + 1] * Bc[dh + 1] * 0.125f;  // c1
        const float wB = Ac[dh + 1] * Bc[dw + 1] * 0.125f;  // c2
        wts[t++] = (g < 2) ? wB : wA;
      }
  }

  // ---- stage x tile (fp32, zero-padded halo, swizzled) ----
  for (int f = tid; f < 6 * 34 * 4; f += 256) {
    const int row = f / 136;
    const int rem = f - row * 136;
    const int col = rem >> 2;
    const int q = rem & 3;
    const int gh = h0 - 1 + row;
    const int gw = w0 - 1 + col;
    floatx4 v = {0.f, 0.f, 0.f, 0.f};
    if ((unsigned)gh < (unsigned)NH && (unsigned)gw < (unsigned)NW)
      v = *reinterpret_cast<const floatx4*>(
          xin + (((size_t)b * NH + gh) * NW + gw) * NC + 4 * q);
    *xsaddr(row, col, q) = v;
  }

  // ---- fire mask: one threefry per cell, wave keeps ballot (bits 0..31) ----
  uint64_t mball;
  {
    const int cellg = (b * NH + h0 + wv) * NW + w0 + (lane & 31);
    uint32_t r0, r1;
    tf2x32(fk0, fk1, 0u, (uint32_t)cellg, r0, r1);
    const uint32_t bits = r0 ^ r1;
    const float u = __uint_as_float((bits >> 9) | 0x3F800000u) - 1.0f;
    mball = __ballot(u > 0.5f);
  }
  __syncthreads();

  const int cc = 2 * (g & 1);   // chunk pair base for this lane's 8 channels
  const int r = wv + 1;
  uint8_t* hbase = ht[wv];

#pragma unroll
  for (int mt = 0; mt < 2; ++mt) {
    const int col = 1 + 16 * mt + c15;

    // center x (identity part of y for groups 0/1)
    const floatx4 xc0 = *xsaddr(r, col, cc);
    const floatx4 xc1 = *xsaddr(r, col, cc + 1);

    // branchless 8-tap sobel over this lane's 8 channels
    float sob[8];
#pragma unroll
    for (int j = 0; j < 8; ++j) sob[j] = 0.f;
    int t = 0;
#pragma unroll
    for (int dh = -1; dh <= 1; ++dh)
#pragma unroll
      for (int dw = -1; dw <= 1; ++dw) {
        if (dh == 0 && dw == 0) continue;
        const floatx4 v0 = *xsaddr(r + dh, col + dw, cc);
        const floatx4 v1 = *xsaddr(r + dh, col + dw, cc + 1);
        const float w = wts[t++];
        sob[0] += w * v0.x; sob[1] += w * v0.y;
        sob[2] += w * v0.z; sob[3] += w * v0.w;
        sob[4] += w * v1.x; sob[5] += w * v1.y;
        sob[6] += w * v1.z; sob[7] += w * v1.w;
      }

    // Y^T B-fragments: a0 -> k 0..31 (x | c1), a1 -> k 32..63 (c2 | pad)
    const bool lo = (g < 2);
    const float xcv[8] = {xc0.x, xc0.y, xc0.z, xc0.w, xc1.x, xc1.y, xc1.z, xc1.w};
    short8 a0, a1;
#pragma unroll
    for (int j = 0; j < 8; ++j) {
      const short sb = bfr(sob[j]);
      a0[j] = lo ? bfr(xcv[j]) : sb;
      a1[j] = lo ? sb : (short)0;
    }

    // GEMM1': 16 MFMAs -> H^T tiles (row o, col cell)
    floatx4 acc[8];
#pragma unroll
    for (int n = 0; n < 8; ++n) acc[n] = bias4[n];
#pragma unroll
    for (int n = 0; n < 8; ++n)
      acc[n] = __builtin_amdgcn_mfma_f32_16x16x32_bf16(w0f[n][0], a0, acc[n], 0, 0, 0);
#pragma unroll
    for (int n = 0; n < 8; ++n)
      acc[n] = __builtin_amdgcn_mfma_f32_16x16x32_bf16(w0f[n][1], a1, acc[n], 0, 0, 0);

    // compiler barrier: prior-iteration ht reads may not sink below the
    // stores (uint32x2 stores vs short8 loads are TBAA-distinct)
    asm volatile("" ::: "memory");

    // relu -> bf16 -> per-wave LDS bounce (XOR swizzle vs 256B-stride conflicts)
#pragma unroll
    for (int n = 0; n < 8; ++n) {
      const float r0 = fmaxf(acc[n].x, 0.f), r1 = fmaxf(acc[n].y, 0.f);
      const float r2 = fmaxf(acc[n].z, 0.f), r3 = fmaxf(acc[n].w, 0.f);
      uint32x2 u;
      u.x = (uint32_t)(uint16_t)bfr(r0) | ((uint32_t)(uint16_t)bfr(r1) << 16);
      u.y = (uint32_t)(uint16_t)bfr(r2) | ((uint32_t)(uint16_t)bfr(r3) << 16);
      int byte = c15 * 256 + (16 * n + 4 * g) * 2;
      byte ^= (c15 & 7) << 4;
      *reinterpret_cast<uint32x2*>(hbase + byte) = u;
    }

    // GEMM2': dx^T = W1 . H   (B-frag = H^T[k=o][cell]), 4 MFMAs
    floatx4 acc2 = {0.f, 0.f, 0.f, 0.f};
#pragma unroll
    for (int s = 0; s < 4; ++s) {
      int byte = c15 * 256 + (32 * s + 8 * g) * 2;
      byte ^= (c15 & 7) << 4;
      const short8 b2 = *reinterpret_cast<short8*>(hbase + byte);
      acc2 = __builtin_amdgcn_mfma_f32_16x16x32_bf16(w1f[s], b2, acc2, 0, 0, 0);
    }

    // update: lane holds dx[ch=4g+reg][cell=c15]; fp32 residual path
    const floatx4 xv = *xsaddr(r, col, g);
    const float mk = (float)((mball >> (16 * mt + c15)) & 1ull);
    const float mk03 = (g == 0) ? 0.f : mk;   // channels 0..2 frozen
    floatx4 ov;
    ov.x = xv.x + acc2.x * mk03;
    ov.y = xv.y + acc2.y * mk03;
    ov.z = xv.z + acc2.z * mk03;
    ov.w = xv.w + acc2.w * mk;
    const size_t cellg = ((size_t)(b * NH + h0 + wv)) * NW + w0 + 16 * mt + c15;
    *reinterpret_cast<floatx4*>(xout + cellg * NC + 4 * g) = ov;
  }
}

extern "C" void kernel_launch(void* const* d_in, const int* in_sizes, int n_in,
                              void* d_out, int out_size, void* d_ws, size_t ws_size,
                              hipStream_t stream) {
  const float* x  = (const float*)d_in[0];
  const float* W0 = (const float*)d_in[1];
  const float* b0 = (const float*)d_in[2];
  const float* W1 = (const float*)d_in[3];
  float* tmp = (float*)d_ws;
  float* out = (float*)d_out;

  uint32_t fa0, fa1, fb0, fb1;
  tf2x32(0u, 42u, 0u, 0u, fa0, fa1);  // fold_in(key(42), 0)
  tf2x32(0u, 42u, 0u, 1u, fb0, fb1);  // fold_in(key(42), 1)

  dim3 grid(NB * (NH / TH) * (NW / TW)), block(256);
  ca_step<<<grid, block, 0, stream>>>(x, tmp, W0, b0, W1, fa0, fa1);
  ca_step<<<grid, block, 0, stream>>>(tmp, out, W0, b0, W1, fb0, fb1);
}

// Round 7
// 95.439 us; speedup vs baseline: 4.7392x; 1.4174x over previous
//
#include <hip/hip_runtime.h>
#include <hip/hip_bf16.h>
#include <stdint.h>

// CA model: B=8, H=256, W=256, C=16, HID=128, steps=2 (fixed by setup_inputs).
// Per step: y=[x,sobel1,sobel2] (48) -> h=relu(y@W0^T+b0) (128) -> dx=h@W1^T (16)
// -> x' = x + dx*mask (channels 3: only). MLP on bf16 MFMA (16x16x32),
// residual/update path in fp32. Mask: JAX threefry2x32 partitionable bits.
// Round 7: tile geometry TH=8 x TW=32 (256 cells/block, 2048 blocks, less
// halo, LDS 38.1KB -> 4 blocks/CU). Body identical to round-4 passing kernel.

#define NB 8
#define NH 256
#define NW 256
#define NC 16
#define TH 8
#define TW 32

typedef __attribute__((ext_vector_type(8))) short short8;
typedef __attribute__((ext_vector_type(4))) float floatx4;
typedef __attribute__((ext_vector_type(2))) uint32_t uint32x2;

__host__ __device__ inline void tf2x32(uint32_t k0, uint32_t k1,
                                       uint32_t x0, uint32_t x1,
                                       uint32_t& o0, uint32_t& o1) {
  const uint32_t ks2 = k0 ^ k1 ^ 0x1BD11BDAu;
  x0 += k0; x1 += k1;
#define RL(v, d) (((v) << (d)) | ((v) >> (32 - (d))))
#define R4(a, b, c, d)                          \
  x0 += x1; x1 = RL(x1, a); x1 ^= x0;           \
  x0 += x1; x1 = RL(x1, b); x1 ^= x0;           \
  x0 += x1; x1 = RL(x1, c); x1 ^= x0;           \
  x0 += x1; x1 = RL(x1, d); x1 ^= x0;
  R4(13, 15, 26, 6);  x0 += k1;  x1 += ks2 + 1u;
  R4(17, 29, 16, 24); x0 += ks2; x1 += k0 + 2u;
  R4(13, 15, 26, 6);  x0 += k0;  x1 += k1 + 3u;
  R4(17, 29, 16, 24); x0 += k1;  x1 += ks2 + 4u;
  R4(13, 15, 26, 6);  x0 += ks2; x1 += k0 + 5u;
#undef R4
#undef RL
  o0 = x0; o1 = x1;
}

__device__ inline short bfr(float x) {
  __hip_bfloat16 h = __float2bfloat16(x);
  return *reinterpret_cast<short*>(&h);
}

__global__ __launch_bounds__(256, 2) void ca_step(
    const float* __restrict__ xin, float* __restrict__ xout,
    const float* __restrict__ W0, const float* __restrict__ b0,
    const float* __restrict__ W1, uint32_t fk0, uint32_t fk1) {
  // fp32 x tile + halo (10 rows x 34 cols), 16B-chunk XOR-swizzled
  __shared__ float xs[10 * 34 * 16];
  __shared__ __align__(16) uint8_t ht[4][4096];   // per-wave H^T bounce (bf16)

  const int tid = threadIdx.x;
  const int bt = blockIdx.x;
  const int wt = bt & 7;
  const int htile = (bt >> 3) & 31;
  const int b = bt >> 8;
  const int h0 = htile * TH;
  const int w0 = wt * TW;

  const int lane = tid & 63;
  const int wv = tid >> 6;
  const int c15 = lane & 15;
  const int g = lane >> 4;

  auto xsaddr = [&](int row, int col, int chunk) -> floatx4* {
    const int off = (row * 34 + col) * 64 + ((chunk ^ ((col >> 1) & 3)) << 4);
    return reinterpret_cast<floatx4*>(reinterpret_cast<char*>(xs) + off);
  };

  // ---- prologue: weight fragments held in VGPRs for whole kernel ----
  // GEMM1': H^T = W0 . Y^T  (A-frag: lane holds A[row=c15][k=8g+j])
  short8 w0f[8][2];
  floatx4 bias4[8];
  short8 w1f[4];
#pragma unroll
  for (int n = 0; n < 8; ++n) {
    const int o = 16 * n + c15;
    const float* p = W0 + o * 48 + 8 * g;
    short8 f;
#pragma unroll
    for (int j = 0; j < 8; ++j) f[j] = bfr(p[j]);
    w0f[n][0] = f;
    short8 f1;
    if (g < 2) {
      const float* p1 = W0 + o * 48 + 32 + 8 * g;
#pragma unroll
      for (int j = 0; j < 8; ++j) f1[j] = bfr(p1[j]);
    } else {
#pragma unroll
      for (int j = 0; j < 8; ++j) f1[j] = 0;   // K-pad 48..63
    }
    w0f[n][1] = f1;
    bias4[n] = *reinterpret_cast<const floatx4*>(b0 + 16 * n + 4 * g);
  }
#pragma unroll
  for (int s = 0; s < 4; ++s) {   // GEMM2': A = W1 [16 ch x 128 o]
    const float* p = W1 + c15 * 128 + 32 * s + 8 * g;
    short8 f;
#pragma unroll
    for (int j = 0; j < 8; ++j) f[j] = bfr(p[j]);
    w1f[s] = f;
  }

  // per-lane sobel tap weights: groups 0/1 produce c2 (sobel2), 2/3 c1 (sobel1)
  float wts[8];
  {
    const float Ac[3] = {1.f, 2.f, 1.f};
    const float Bc[3] = {-1.f, 0.f, 1.f};
    int t = 0;
#pragma unroll
    for (int dh = -1; dh <= 1; ++dh)
#pragma unroll
      for (int dw = -1; dw <= 1; ++dw) {
        if (dh == 0 && dw == 0) continue;
        const float wA = Ac[dw + 1] * Bc[dh + 1] * 0.125f;  // c1
        const float wB = Ac[dh + 1] * Bc[dw + 1] * 0.125f;  // c2
        wts[t++] = (g < 2) ? wB : wA;
      }
  }

  // ---- stage x tile (fp32, zero-padded halo, swizzled) ----
  for (int f = tid; f < 10 * 34 * 4; f += 256) {
    const int row = f / 136;
    const int rem = f - row * 136;
    const int col = rem >> 2;
    const int q = rem & 3;
    const int gh = h0 - 1 + row;
    const int gw = w0 - 1 + col;
    floatx4 v = {0.f, 0.f, 0.f, 0.f};
    if ((unsigned)gh < (unsigned)NH && (unsigned)gw < (unsigned)NW)
      v = *reinterpret_cast<const floatx4*>(
          xin + (((size_t)b * NH + gh) * NW + gw) * NC + 4 * q);
    *xsaddr(row, col, q) = v;
  }

  // ---- fire mask: wave wv owns rows 2wv,2wv+1 x 32 cols; bit lane =
  // (rowparity<<5) | col ----
  uint64_t mball;
  {
    const int cellg = (b * NH + h0 + 2 * wv + (lane >> 5)) * NW + w0 + (lane & 31);
    uint32_t r0, r1;
    tf2x32(fk0, fk1, 0u, (uint32_t)cellg, r0, r1);
    const uint32_t bits = r0 ^ r1;
    const float u = __uint_as_float((bits >> 9) | 0x3F800000u) - 1.0f;
    mball = __ballot(u > 0.5f);
  }
  __syncthreads();

  const int cc = 2 * (g & 1);   // chunk pair base for this lane's 8 channels
  uint8_t* hbase = ht[wv];

#pragma unroll
  for (int mt = 0; mt < 4; ++mt) {
    const int rp = mt >> 1;             // row parity within wave's pair
    const int chh = mt & 1;             // col half
    const int r = 1 + 2 * wv + rp;
    const int col = 1 + 16 * chh + c15;

    // center x (identity part of y for groups 0/1)
    const floatx4 xc0 = *xsaddr(r, col, cc);
    const floatx4 xc1 = *xsaddr(r, col, cc + 1);

    // branchless 8-tap sobel over this lane's 8 channels
    float sob[8];
#pragma unroll
    for (int j = 0; j < 8; ++j) sob[j] = 0.f;
    int t = 0;
#pragma unroll
    for (int dh = -1; dh <= 1; ++dh)
#pragma unroll
      for (int dw = -1; dw <= 1; ++dw) {
        if (dh == 0 && dw == 0) continue;
        const floatx4 v0 = *xsaddr(r + dh, col + dw, cc);
        const floatx4 v1 = *xsaddr(r + dh, col + dw, cc + 1);
        const float w = wts[t++];
        sob[0] += w * v0.x; sob[1] += w * v0.y;
        sob[2] += w * v0.z; sob[3] += w * v0.w;
        sob[4] += w * v1.x; sob[5] += w * v1.y;
        sob[6] += w * v1.z; sob[7] += w * v1.w;
      }

    // Y^T B-fragments: a0 -> k 0..31 (x | c1), a1 -> k 32..63 (c2 | pad)
    const bool lo = (g < 2);
    const float xcv[8] = {xc0.x, xc0.y, xc0.z, xc0.w, xc1.x, xc1.y, xc1.z, xc1.w};
    short8 a0, a1;
#pragma unroll
    for (int j = 0; j < 8; ++j) {
      const short sb = bfr(sob[j]);
      a0[j] = lo ? bfr(xcv[j]) : sb;
      a1[j] = lo ? sb : (short)0;
    }

    // GEMM1': 16 MFMAs -> H^T tiles (row o, col cell)
    floatx4 acc[8];
#pragma unroll
    for (int n = 0; n < 8; ++n) acc[n] = bias4[n];
#pragma unroll
    for (int n = 0; n < 8; ++n)
      acc[n] = __builtin_amdgcn_mfma_f32_16x16x32_bf16(w0f[n][0], a0, acc[n], 0, 0, 0);
#pragma unroll
    for (int n = 0; n < 8; ++n)
      acc[n] = __builtin_amdgcn_mfma_f32_16x16x32_bf16(w0f[n][1], a1, acc[n], 0, 0, 0);

    // compiler barrier: prior-iteration ht reads may not sink below the
    // stores (uint32x2 stores vs short8 loads are TBAA-distinct)
    asm volatile("" ::: "memory");

    // relu -> bf16 -> per-wave LDS bounce (XOR swizzle vs 256B-stride conflicts)
#pragma unroll
    for (int n = 0; n < 8; ++n) {
      const float r0 = fmaxf(acc[n].x, 0.f), r1 = fmaxf(acc[n].y, 0.f);
      const float r2 = fmaxf(acc[n].z, 0.f), r3 = fmaxf(acc[n].w, 0.f);
      uint32x2 u;
      u.x = (uint32_t)(uint16_t)bfr(r0) | ((uint32_t)(uint16_t)bfr(r1) << 16);
      u.y = (uint32_t)(uint16_t)bfr(r2) | ((uint32_t)(uint16_t)bfr(r3) << 16);
      int byte = c15 * 256 + (16 * n + 4 * g) * 2;
      byte ^= (c15 & 7) << 4;
      *reinterpret_cast<uint32x2*>(hbase + byte) = u;
    }

    // GEMM2': dx^T = W1 . H   (B-frag = H^T[k=o][cell]), 4 MFMAs
    floatx4 acc2 = {0.f, 0.f, 0.f, 0.f};
#pragma unroll
    for (int s = 0; s < 4; ++s) {
      int byte = c15 * 256 + (32 * s + 8 * g) * 2;
      byte ^= (c15 & 7) << 4;
      const short8 b2 = *reinterpret_cast<short8*>(hbase + byte);
      acc2 = __builtin_amdgcn_mfma_f32_16x16x32_bf16(w1f[s], b2, acc2, 0, 0, 0);
    }

    // update: lane holds dx[ch=4g+reg][cell=c15]; fp32 residual path
    const floatx4 xv = *xsaddr(r, col, g);
    const float mk = (float)((mball >> (32 * rp + 16 * chh + c15)) & 1ull);
    const float mk03 = (g == 0) ? 0.f : mk;   // channels 0..2 frozen
    floatx4 ov;
    ov.x = xv.x + acc2.x * mk03;
    ov.y = xv.y + acc2.y * mk03;
    ov.z = xv.z + acc2.z * mk03;
    ov.w = xv.w + acc2.w * mk;
    const size_t cellg =
        ((size_t)(b * NH + h0 + 2 * wv + rp)) * NW + w0 + 16 * chh + c15;
    *reinterpret_cast<floatx4*>(xout + cellg * NC + 4 * g) = ov;
  }
}

extern "C" void kernel_launch(void* const* d_in, const int* in_sizes, int n_in,
                              void* d_out, int out_size, void* d_ws, size_t ws_size,
                              hipStream_t stream) {
  const float* x  = (const float*)d_in[0];
  const float* W0 = (const float*)d_in[1];
  const float* b0 = (const float*)d_in[2];
  const float* W1 = (const float*)d_in[3];
  float* tmp = (float*)d_ws;
  float* out = (float*)d_out;

  uint32_t fa0, fa1, fb0, fb1;
  tf2x32(0u, 42u, 0u, 0u, fa0, fa1);  // fold_in(key(42), 0)
  tf2x32(0u, 42u, 0u, 1u, fb0, fb1);  // fold_in(key(42), 1)

  dim3 grid(NB * (NH / TH) * (NW / TW)), block(256);
  ca_step<<<grid, block, 0, stream>>>(x, tmp, W0, b0, W1, fa0, fa1);
  ca_step<<<grid, block, 0, stream>>>(tmp, out, W0, b0, W1, fb0, fb1);
}

// Round 8
// 91.011 us; speedup vs baseline: 4.9697x; 1.0486x over previous
//
#include <hip/hip_runtime.h>
#include <hip/hip_bf16.h>
#include <stdint.h>

// CA model: B=8, H=256, W=256, C=16, HID=128, steps=2 (fixed by setup_inputs).
// Per step: y=[x,sobel1,sobel2] (48) -> h=relu(y@W0^T+b0) (128) -> dx=h@W1^T (16)
// -> x' = x + dx*mask (channels 3: only). MLP on bf16 MFMA (16x16x32),
// residual/update path in fp32. Mask: JAX threefry2x32 partitionable bits.
// Round 8: hidden-dim permutation trick — GEMM2's W1 k-order is permuted by
// tau(s, 8g+j) = 32s + 16*(j>>2) + 4g + (j&3) so that GEMM2's B-fragment is
// exactly the lane's own relu'd GEMM1 accumulators (o is contracted, so any
// consistent permutation is exact). The ht LDS bounce (12 LDS ops + barrier
// per mt, the bank-conflict source) is deleted entirely.

#define NB 8
#define NH 256
#define NW 256
#define NC 16
#define TH 8
#define TW 32

typedef __attribute__((ext_vector_type(8))) short short8;
typedef __attribute__((ext_vector_type(4))) float floatx4;

__host__ __device__ inline void tf2x32(uint32_t k0, uint32_t k1,
                                       uint32_t x0, uint32_t x1,
                                       uint32_t& o0, uint32_t& o1) {
  const uint32_t ks2 = k0 ^ k1 ^ 0x1BD11BDAu;
  x0 += k0; x1 += k1;
#define RL(v, d) (((v) << (d)) | ((v) >> (32 - (d))))
#define R4(a, b, c, d)                          \
  x0 += x1; x1 = RL(x1, a); x1 ^= x0;           \
  x0 += x1; x1 = RL(x1, b); x1 ^= x0;           \
  x0 += x1; x1 = RL(x1, c); x1 ^= x0;           \
  x0 += x1; x1 = RL(x1, d); x1 ^= x0;
  R4(13, 15, 26, 6);  x0 += k1;  x1 += ks2 + 1u;
  R4(17, 29, 16, 24); x0 += ks2; x1 += k0 + 2u;
  R4(13, 15, 26, 6);  x0 += k0;  x1 += k1 + 3u;
  R4(17, 29, 16, 24); x0 += k1;  x1 += ks2 + 4u;
  R4(13, 15, 26, 6);  x0 += ks2; x1 += k0 + 5u;
#undef R4
#undef RL
  o0 = x0; o1 = x1;
}

__device__ inline short bfr(float x) {
  __hip_bfloat16 h = __float2bfloat16(x);
  return *reinterpret_cast<short*>(&h);
}

__global__ __launch_bounds__(256, 2) void ca_step(
    const float* __restrict__ xin, float* __restrict__ xout,
    const float* __restrict__ W0, const float* __restrict__ b0,
    const float* __restrict__ W1, uint32_t fk0, uint32_t fk1) {
  // fp32 x tile + halo (10 rows x 34 cols), 16B-chunk XOR-swizzled
  __shared__ float xs[10 * 34 * 16];

  const int tid = threadIdx.x;
  const int bt = blockIdx.x;
  const int wt = bt & 7;
  const int htile = (bt >> 3) & 31;
  const int b = bt >> 8;
  const int h0 = htile * TH;
  const int w0 = wt * TW;

  const int lane = tid & 63;
  const int wv = tid >> 6;
  const int c15 = lane & 15;
  const int g = lane >> 4;

  auto xsaddr = [&](int row, int col, int chunk) -> floatx4* {
    const int off = (row * 34 + col) * 64 + ((chunk ^ ((col >> 1) & 3)) << 4);
    return reinterpret_cast<floatx4*>(reinterpret_cast<char*>(xs) + off);
  };

  // ---- prologue: weight fragments held in VGPRs for whole kernel ----
  // GEMM1': H^T = W0 . Y^T  (A-frag: lane holds A[row=c15][k=8g+j])
  short8 w0f[8][2];
  floatx4 bias4[8];
  short8 w1f[4];
#pragma unroll
  for (int n = 0; n < 8; ++n) {
    const int o = 16 * n + c15;
    const float* p = W0 + o * 48 + 8 * g;
    short8 f;
#pragma unroll
    for (int j = 0; j < 8; ++j) f[j] = bfr(p[j]);
    w0f[n][0] = f;
    short8 f1;
    if (g < 2) {
      const float* p1 = W0 + o * 48 + 32 + 8 * g;
#pragma unroll
      for (int j = 0; j < 8; ++j) f1[j] = bfr(p1[j]);
    } else {
#pragma unroll
      for (int j = 0; j < 8; ++j) f1[j] = 0;   // K-pad 48..63
    }
    w0f[n][1] = f1;
    bias4[n] = *reinterpret_cast<const floatx4*>(b0 + 16 * n + 4 * g);
  }
  // GEMM2': A = W1 [16 ch x 128 o], k-order permuted by tau so the B-frag
  // is the lane's own GEMM1 accumulators: tau(s,8g+j)=32s+16*(j>>2)+4g+(j&3)
#pragma unroll
  for (int s = 0; s < 4; ++s) {
    const float* p = W1 + c15 * 128;
    short8 f;
#pragma unroll
    for (int j = 0; j < 8; ++j)
      f[j] = bfr(p[32 * s + 16 * (j >> 2) + 4 * g + (j & 3)]);
    w1f[s] = f;
  }

  // per-lane sobel tap weights: groups 0/1 produce c2 (sobel2), 2/3 c1 (sobel1)
  float wts[8];
  {
    const float Ac[3] = {1.f, 2.f, 1.f};
    const float Bc[3] = {-1.f, 0.f, 1.f};
    int t = 0;
#pragma unroll
    for (int dh = -1; dh <= 1; ++dh)
#pragma unroll
      for (int dw = -1; dw <= 1; ++dw) {
        if (dh == 0 && dw == 0) continue;
        const float wA = Ac[dw + 1] * Bc[dh + 1] * 0.125f;  // c1
        const float wB = Ac[dh + 1] * Bc[dw + 1] * 0.125f;  // c2
        wts[t++] = (g < 2) ? wB : wA;
      }
  }

  // ---- stage x tile (fp32, zero-padded halo, swizzled) ----
  for (int f = tid; f < 10 * 34 * 4; f += 256) {
    const int row = f / 136;
    const int rem = f - row * 136;
    const int col = rem >> 2;
    const int q = rem & 3;
    const int gh = h0 - 1 + row;
    const int gw = w0 - 1 + col;
    floatx4 v = {0.f, 0.f, 0.f, 0.f};
    if ((unsigned)gh < (unsigned)NH && (unsigned)gw < (unsigned)NW)
      v = *reinterpret_cast<const floatx4*>(
          xin + (((size_t)b * NH + gh) * NW + gw) * NC + 4 * q);
    *xsaddr(row, col, q) = v;
  }

  // ---- fire mask: wave wv owns rows 2wv,2wv+1 x 32 cols; bit lane =
  // (rowparity<<5) | col ----
  uint64_t mball;
  {
    const int cellg = (b * NH + h0 + 2 * wv + (lane >> 5)) * NW + w0 + (lane & 31);
    uint32_t r0, r1;
    tf2x32(fk0, fk1, 0u, (uint32_t)cellg, r0, r1);
    const uint32_t bits = r0 ^ r1;
    const float u = __uint_as_float((bits >> 9) | 0x3F800000u) - 1.0f;
    mball = __ballot(u > 0.5f);
  }
  __syncthreads();

  const int cc = 2 * (g & 1);   // chunk pair base for this lane's 8 channels

#pragma unroll
  for (int mt = 0; mt < 4; ++mt) {
    const int rp = mt >> 1;             // row parity within wave's pair
    const int chh = mt & 1;             // col half
    const int r = 1 + 2 * wv + rp;
    const int col = 1 + 16 * chh + c15;

    // center x (identity part of y for groups 0/1)
    const floatx4 xc0 = *xsaddr(r, col, cc);
    const floatx4 xc1 = *xsaddr(r, col, cc + 1);

    // branchless 8-tap sobel over this lane's 8 channels
    float sob[8];
#pragma unroll
    for (int j = 0; j < 8; ++j) sob[j] = 0.f;
    int t = 0;
#pragma unroll
    for (int dh = -1; dh <= 1; ++dh)
#pragma unroll
      for (int dw = -1; dw <= 1; ++dw) {
        if (dh == 0 && dw == 0) continue;
        const floatx4 v0 = *xsaddr(r + dh, col + dw, cc);
        const floatx4 v1 = *xsaddr(r + dh, col + dw, cc + 1);
        const float w = wts[t++];
        sob[0] += w * v0.x; sob[1] += w * v0.y;
        sob[2] += w * v0.z; sob[3] += w * v0.w;
        sob[4] += w * v1.x; sob[5] += w * v1.y;
        sob[6] += w * v1.z; sob[7] += w * v1.w;
      }

    // Y^T B-fragments: a0 -> k 0..31 (x | c1), a1 -> k 32..63 (c2 | pad)
    const bool lo = (g < 2);
    const float xcv[8] = {xc0.x, xc0.y, xc0.z, xc0.w, xc1.x, xc1.y, xc1.z, xc1.w};
    short8 a0, a1;
#pragma unroll
    for (int j = 0; j < 8; ++j) {
      const short sb = bfr(sob[j]);
      a0[j] = lo ? bfr(xcv[j]) : sb;
      a1[j] = lo ? sb : (short)0;
    }

    // GEMM1': 16 MFMAs -> H^T tiles; lane holds H^T[o=16n+4g+r][cell=c15]
    floatx4 acc[8];
#pragma unroll
    for (int n = 0; n < 8; ++n) acc[n] = bias4[n];
#pragma unroll
    for (int n = 0; n < 8; ++n)
      acc[n] = __builtin_amdgcn_mfma_f32_16x16x32_bf16(w0f[n][0], a0, acc[n], 0, 0, 0);
#pragma unroll
    for (int n = 0; n < 8; ++n)
      acc[n] = __builtin_amdgcn_mfma_f32_16x16x32_bf16(w0f[n][1], a1, acc[n], 0, 0, 0);

    // GEMM2': dx^T = W1 . H with permuted k-order; B-frag is the lane's own
    // relu'd accumulators: b2[j] = bf16(relu(acc[2s + (j>>2)][j&3]))
    floatx4 acc2 = {0.f, 0.f, 0.f, 0.f};
#pragma unroll
    for (int s = 0; s < 4; ++s) {
      short8 b2;
#pragma unroll
      for (int j = 0; j < 8; ++j)
        b2[j] = bfr(fmaxf(acc[2 * s + (j >> 2)][j & 3], 0.f));
      acc2 = __builtin_amdgcn_mfma_f32_16x16x32_bf16(w1f[s], b2, acc2, 0, 0, 0);
    }

    // update: lane holds dx[ch=4g+reg][cell=c15]; fp32 residual path
    const floatx4 xv = *xsaddr(r, col, g);
    const float mk = (float)((mball >> (32 * rp + 16 * chh + c15)) & 1ull);
    const float mk03 = (g == 0) ? 0.f : mk;   // channels 0..2 frozen
    floatx4 ov;
    ov.x = xv.x + acc2.x * mk03;
    ov.y = xv.y + acc2.y * mk03;
    ov.z = xv.z + acc2.z * mk03;
    ov.w = xv.w + acc2.w * mk;
    const size_t cellg =
        ((size_t)(b * NH + h0 + 2 * wv + rp)) * NW + w0 + 16 * chh + c15;
    *reinterpret_cast<floatx4*>(xout + cellg * NC + 4 * g) = ov;
  }
}

extern "C" void kernel_launch(void* const* d_in, const int* in_sizes, int n_in,
                              void* d_out, int out_size, void* d_ws, size_t ws_size,
                              hipStream_t stream) {
  const float* x  = (const float*)d_in[0];
  const float* W0 = (const float*)d_in[1];
  const float* b0 = (const float*)d_in[2];
  const float* W1 = (const float*)d_in[3];
  float* tmp = (float*)d_ws;
  float* out = (float*)d_out;

  uint32_t fa0, fa1, fb0, fb1;
  tf2x32(0u, 42u, 0u, 0u, fa0, fa1);  // fold_in(key(42), 0)
  tf2x32(0u, 42u, 0u, 1u, fb0, fb1);  // fold_in(key(42), 1)

  dim3 grid(NB * (NH / TH) * (NW / TW)), block(256);
  ca_step<<<grid, block, 0, stream>>>(x, tmp, W0, b0, W1, fa0, fa1);
  ca_step<<<grid, block, 0, stream>>>(tmp, out, W0, b0, W1, fb0, fb1);
}